// Round 1
// baseline (1324.172 us; speedup 1.0000x reference)
//
#include <hip/hip_runtime.h>
#include <hip/hip_bf16.h>

#define SEQ   4096
#define MDIM  2048
#define NHEADS 16
#define HDIM  128

typedef __attribute__((ext_vector_type(8))) short bf16x8;
typedef __attribute__((ext_vector_type(4))) float f32x4;

__device__ __forceinline__ short f2bf(float f) {
  unsigned u = __float_as_uint(f);
  u += 0x7fffu + ((u >> 16) & 1u);   // RNE
  return (short)(u >> 16);
}

// ---------------- fp32 -> bf16 elementwise (vectorized) ----------------
__global__ __launch_bounds__(256) void k_conv(const float* __restrict__ in,
                                              short* __restrict__ out, int n4) {
  int i = blockIdx.x * 256 + threadIdx.x;
  if (i >= n4) return;
  float4 v = ((const float4*)in)[i];
  ushort4 o;
  o.x = (unsigned short)f2bf(v.x);
  o.y = (unsigned short)f2bf(v.y);
  o.z = (unsigned short)f2bf(v.z);
  o.w = (unsigned short)f2bf(v.w);
  ((ushort4*)out)[i] = o;
}

// ---------------- W [K][N] fp32 -> Wt [N][K] bf16 (tiled transpose) ----------------
__global__ __launch_bounds__(256) void k_transpose(const float* __restrict__ W,
                                                   short* __restrict__ Wt) {
  __shared__ short tile[64][65];
  const int n0 = blockIdx.x * 64, k0 = blockIdx.y * 64;
  const int t = threadIdx.x;
  for (int i = 0; i < 4; ++i) {
    int li = i * 256 + t;              // 0..1023
    int row = li >> 4, c4 = (li & 15) * 4;
    float4 v = *(const float4*)&W[(size_t)(k0 + row) * MDIM + n0 + c4];
    tile[row][c4 + 0] = f2bf(v.x);
    tile[row][c4 + 1] = f2bf(v.y);
    tile[row][c4 + 2] = f2bf(v.z);
    tile[row][c4 + 3] = f2bf(v.w);
  }
  __syncthreads();
  for (int i = 0; i < 4; ++i) {
    int li = i * 256 + t;
    int nn = li >> 4, k4 = (li & 15) * 4;
    ushort4 o;
    o.x = (unsigned short)tile[k4 + 0][nn];
    o.y = (unsigned short)tile[k4 + 1][nn];
    o.z = (unsigned short)tile[k4 + 2][nn];
    o.w = (unsigned short)tile[k4 + 3][nn];
    *(ushort4*)&Wt[(size_t)(n0 + nn) * MDIM + k0 + k4] = o;
  }
}

// ---------------- bf16 GEMM: C[M,N] = A[M,K] * Bt[N,K]^T + bias ----------------
// m97 structure: 128x128 tile, BK=64, 4 waves (2x2, 64x64 each), global_load_lds w=16.
// EPI 0: C row-major bf16 [M][N], values scaled by oscale.
// EPI 1: C transposed bf16 [N][M] (for V -> Vt).
template <int EPI>
__global__ __launch_bounds__(256) void k_gemm(const short* __restrict__ A,
                                              const short* __restrict__ Bt,
                                              const float* __restrict__ bias,
                                              short* __restrict__ C,
                                              int M, int N, int K, float oscale) {
  __shared__ short As[128 * 64];
  __shared__ short Bs[128 * 64];
  const int t = threadIdx.x;
  const int lane = t & 63, w = t >> 6;
  const int r = lane & 15, g = lane >> 4;
  const int wr = w >> 1, wc = w & 1;
  const int m0 = blockIdx.y * 128, n0 = blockIdx.x * 128;

  f32x4 acc[4][4] = {};

  for (int k0 = 0; k0 < K; k0 += 64) {
    // stage 16KB A-tile + 16KB B-tile: per wave 4 chunks of 1KB each
    for (int it = 0; it < 4; ++it) {
      int chunk = it * 4 + w;               // 0..15
      int li = chunk * 64 + lane;           // 0..1023
      int row = li >> 3, cv = li & 7;       // row 0..127, 8-bf16 col group
      const short* gA = A + (size_t)(m0 + row) * K + k0 + cv * 8;
      const short* gB = Bt + (size_t)(n0 + row) * K + k0 + cv * 8;
      __builtin_amdgcn_global_load_lds((const __attribute__((address_space(1))) void*)gA,
                                       (__attribute__((address_space(3))) void*)(As + chunk * 512),
                                       16, 0, 0);
      __builtin_amdgcn_global_load_lds((const __attribute__((address_space(1))) void*)gB,
                                       (__attribute__((address_space(3))) void*)(Bs + chunk * 512),
                                       16, 0, 0);
    }
    __syncthreads();

    for (int kk = 0; kk < 64; kk += 32) {
      bf16x8 a[4], b[4];
#pragma unroll
      for (int m = 0; m < 4; ++m)
        a[m] = *(const bf16x8*)&As[(wr * 64 + m * 16 + r) * 64 + kk + 8 * g];
#pragma unroll
      for (int n = 0; n < 4; ++n)
        b[n] = *(const bf16x8*)&Bs[(wc * 64 + n * 16 + r) * 64 + kk + 8 * g];
#pragma unroll
      for (int m = 0; m < 4; ++m)
#pragma unroll
        for (int n = 0; n < 4; ++n)
          acc[m][n] = __builtin_amdgcn_mfma_f32_16x16x32_bf16(a[m], b[n], acc[m][n], 0, 0, 0);
    }
    __syncthreads();
  }

  // epilogue: C/D layout col = lane&15, row = (lane>>4)*4 + j
#pragma unroll
  for (int n = 0; n < 4; ++n) {
    int col = n0 + wc * 64 + n * 16 + r;
    float bv = bias[col];
#pragma unroll
    for (int m = 0; m < 4; ++m) {
      int rowb = m0 + wr * 64 + m * 16 + g * 4;
      if (EPI == 0) {
#pragma unroll
        for (int j = 0; j < 4; ++j)
          C[(size_t)(rowb + j) * N + col] = f2bf((acc[m][n][j] + bv) * oscale);
      } else {
        ushort4 o;
        o.x = (unsigned short)f2bf((acc[m][n][0] + bv) * oscale);
        o.y = (unsigned short)f2bf((acc[m][n][1] + bv) * oscale);
        o.z = (unsigned short)f2bf((acc[m][n][2] + bv) * oscale);
        o.w = (unsigned short)f2bf((acc[m][n][3] + bv) * oscale);
        *(ushort4*)&C[(size_t)col * M + rowb] = o;   // C is [N][M]
      }
    }
  }
}

// ---------------- flash attention ----------------
// grid (SEQ/64, NHEADS); 4 waves/block, wave w owns q rows q0 = bx*64+w*16 .. +16.
// Q pre-scaled by 1/sqrt(hd) in its GEMM epilogue. Vt is [MDIM][SEQ].
__global__ __launch_bounds__(256) void k_attn(const short* __restrict__ Qb,
                                              const short* __restrict__ Kb,
                                              const short* __restrict__ Vt,
                                              float* __restrict__ Out) {
  __shared__ __align__(16) short Plds[4][16][32];
  const int t = threadIdx.x;
  const int lane = t & 63, w = t >> 6;
  const int r = lane & 15, g = lane >> 4;
  const int h = blockIdx.y;
  const int q0 = blockIdx.x * 64 + w * 16;
  const int hoff = h * HDIM;

  bf16x8 qf[4];
#pragma unroll
  for (int kk = 0; kk < 4; ++kk)
    qf[kk] = *(const bf16x8*)&Qb[(size_t)(q0 + r) * MDIM + hoff + kk * 32 + 8 * g];

  f32x4 o[8] = {};
  float mrun[4] = {-3.0e38f, -3.0e38f, -3.0e38f, -3.0e38f};
  float lsum[4] = {0.f, 0.f, 0.f, 0.f};

  for (int t0 = 0; t0 < SEQ; t0 += 32) {
    f32x4 s0 = {}, s1 = {};
#pragma unroll
    for (int kk = 0; kk < 4; ++kk) {
      bf16x8 k0f = *(const bf16x8*)&Kb[(size_t)(t0 + r) * MDIM + hoff + kk * 32 + 8 * g];
      bf16x8 k1f = *(const bf16x8*)&Kb[(size_t)(t0 + 16 + r) * MDIM + hoff + kk * 32 + 8 * g];
      s0 = __builtin_amdgcn_mfma_f32_16x16x32_bf16(qf[kk], k0f, s0, 0, 0, 0);
      s1 = __builtin_amdgcn_mfma_f32_16x16x32_bf16(qf[kk], k1f, s1, 0, 0, 0);
    }

    float al[4];
#pragma unroll
    for (int j = 0; j < 4; ++j) {
      float x0 = s0[j], x1 = s1[j];
      float tm = fmaxf(x0, x1);
      tm = fmaxf(tm, __shfl_xor(tm, 1));
      tm = fmaxf(tm, __shfl_xor(tm, 2));
      tm = fmaxf(tm, __shfl_xor(tm, 4));
      tm = fmaxf(tm, __shfl_xor(tm, 8));
      float mn = fmaxf(mrun[j], tm);
      al[j] = __expf(mrun[j] - mn);
      mrun[j] = mn;
      float p0 = __expf(x0 - mn), p1 = __expf(x1 - mn);
      float rs = p0 + p1;
      rs += __shfl_xor(rs, 1);
      rs += __shfl_xor(rs, 2);
      rs += __shfl_xor(rs, 4);
      rs += __shfl_xor(rs, 8);
      lsum[j] = lsum[j] * al[j] + rs;
      // D-layout (row = 4g+j, col = r) -> LDS for A-frag transpose
      Plds[w][g * 4 + j][r] = f2bf(p0);
      Plds[w][g * 4 + j][16 + r] = f2bf(p1);
    }
#pragma unroll
    for (int n = 0; n < 8; ++n) {
      o[n][0] *= al[0]; o[n][1] *= al[1]; o[n][2] *= al[2]; o[n][3] *= al[3];
    }
    // cross-lane LDS RAW within the wave: DS pipe is in-order per wave; just
    // stop the compiler from reordering the (per-thread disjoint) accesses.
    __syncthreads();
    bf16x8 pa = *(const bf16x8*)&Plds[w][r][8 * g];
#pragma unroll
    for (int n = 0; n < 8; ++n) {
      bf16x8 vb = *(const bf16x8*)&Vt[(size_t)(hoff + n * 16 + r) * SEQ + t0 + 8 * g];
      o[n] = __builtin_amdgcn_mfma_f32_16x16x32_bf16(pa, vb, o[n], 0, 0, 0);
    }
    __syncthreads();
  }

  float rl[4];
#pragma unroll
  for (int j = 0; j < 4; ++j) rl[j] = 1.0f / lsum[j];
#pragma unroll
  for (int n = 0; n < 8; ++n)
#pragma unroll
    for (int j = 0; j < 4; ++j)
      Out[(size_t)(q0 + g * 4 + j) * MDIM + hoff + n * 16 + r] = o[n][j] * rl[j];
}

extern "C" void kernel_launch(void* const* d_in, const int* in_sizes, int n_in,
                              void* d_out, int out_size, void* d_ws, size_t ws_size,
                              hipStream_t stream) {
  const float* query  = (const float*)d_in[0];
  const float* key_in = (const float*)d_in[1];
  const float* value  = (const float*)d_in[2];
  const float* Wq = (const float*)d_in[3];
  const float* bq = (const float*)d_in[4];
  const float* Wk = (const float*)d_in[5];
  const float* bk = (const float*)d_in[6];
  const float* Wv = (const float*)d_in[7];
  const float* bv = (const float*)d_in[8];
  float* out = (float*)d_out;

  // workspace layout (bf16 shorts): Xb[S*D] Wtb[D*D] Qb[S*D] Kb[S*D] Vt[D*S] = 72 MB
  short* Xb  = (short*)d_ws;
  short* Wtb = Xb + (size_t)SEQ * MDIM;
  short* Qb  = Wtb + (size_t)MDIM * MDIM;
  short* Kb  = Qb + (size_t)SEQ * MDIM;
  short* Vt  = Kb + (size_t)SEQ * MDIM;

  const int n4x = SEQ * MDIM / 4;            // 2,097,152
  dim3 gConv(n4x / 256);
  dim3 gTr(MDIM / 64, MDIM / 64);
  dim3 gGemm(MDIM / 128, SEQ / 128);
  dim3 gAttn(SEQ / 64, NHEADS);
  const float qscale = 0.08838834764831845f; // 1/sqrt(128)

  // Q = (query @ Wq + bq) * qscale
  k_conv<<<gConv, 256, 0, stream>>>(query, Xb, n4x);
  k_transpose<<<gTr, 256, 0, stream>>>(Wq, Wtb);
  k_gemm<0><<<gGemm, 256, 0, stream>>>(Xb, Wtb, bq, Qb, SEQ, MDIM, MDIM, qscale);
  // K = key_in @ Wk + bk
  k_conv<<<gConv, 256, 0, stream>>>(key_in, Xb, n4x);
  k_transpose<<<gTr, 256, 0, stream>>>(Wk, Wtb);
  k_gemm<0><<<gGemm, 256, 0, stream>>>(Xb, Wtb, bk, Kb, SEQ, MDIM, MDIM, 1.0f);
  // Vt = (value @ Wv + bv)^T
  k_conv<<<gConv, 256, 0, stream>>>(value, Xb, n4x);
  k_transpose<<<gTr, 256, 0, stream>>>(Wv, Wtb);
  k_gemm<1><<<gGemm, 256, 0, stream>>>(Xb, Wtb, bv, Vt, SEQ, MDIM, MDIM, 1.0f);
  // attention
  k_attn<<<gAttn, 256, 0, stream>>>(Qb, Kb, Vt, out);
}

// Round 3
// 826.373 us; speedup vs baseline: 1.6024x; 1.6024x over previous
//
#include <hip/hip_runtime.h>
#include <hip/hip_bf16.h>

#define SEQ   4096
#define MDIM  2048
#define NHEADS 16
#define HDIM  128

typedef __attribute__((ext_vector_type(8))) short bf16x8;
typedef __attribute__((ext_vector_type(4))) float f32x4;
typedef __attribute__((ext_vector_type(16))) float f32x16;
typedef __attribute__((ext_vector_type(2))) unsigned int u32x2;
typedef __attribute__((ext_vector_type(4))) unsigned int u32x4;

__device__ __forceinline__ short f2bf(float f) {
  unsigned u = __float_as_uint(f);
  u += 0x7fffu + ((u >> 16) & 1u);   // RNE
  return (short)(u >> 16);
}

// ---------------- fp32 -> bf16 elementwise (vectorized) ----------------
__global__ __launch_bounds__(256) void k_conv(const float* __restrict__ in,
                                              short* __restrict__ out, int n4) {
  int i = blockIdx.x * 256 + threadIdx.x;
  if (i >= n4) return;
  float4 v = ((const float4*)in)[i];
  ushort4 o;
  o.x = (unsigned short)f2bf(v.x);
  o.y = (unsigned short)f2bf(v.y);
  o.z = (unsigned short)f2bf(v.z);
  o.w = (unsigned short)f2bf(v.w);
  ((ushort4*)out)[i] = o;
}

// ---------------- W [K][N] fp32 -> Wt [N][K] bf16 (tiled transpose) ----------------
__global__ __launch_bounds__(256) void k_transpose(const float* __restrict__ W,
                                                   short* __restrict__ Wt) {
  __shared__ short tile[64][65];
  const int n0 = blockIdx.x * 64, k0 = blockIdx.y * 64;
  const int t = threadIdx.x;
  for (int i = 0; i < 4; ++i) {
    int li = i * 256 + t;              // 0..1023
    int row = li >> 4, c4 = (li & 15) * 4;
    float4 v = *(const float4*)&W[(size_t)(k0 + row) * MDIM + n0 + c4];
    tile[row][c4 + 0] = f2bf(v.x);
    tile[row][c4 + 1] = f2bf(v.y);
    tile[row][c4 + 2] = f2bf(v.z);
    tile[row][c4 + 3] = f2bf(v.w);
  }
  __syncthreads();
  for (int i = 0; i < 4; ++i) {
    int li = i * 256 + t;
    int nn = li >> 4, k4 = (li & 15) * 4;
    ushort4 o;
    o.x = (unsigned short)tile[k4 + 0][nn];
    o.y = (unsigned short)tile[k4 + 1][nn];
    o.z = (unsigned short)tile[k4 + 2][nn];
    o.w = (unsigned short)tile[k4 + 3][nn];
    *(ushort4*)&Wt[(size_t)(n0 + nn) * MDIM + k0 + k4] = o;
  }
}

// ---------------- bf16 GEMM: C[M,N] = A[M,K] * Bt[N,K]^T + bias ----------------
template <int EPI>
__global__ __launch_bounds__(256) void k_gemm(const short* __restrict__ A,
                                              const short* __restrict__ Bt,
                                              const float* __restrict__ bias,
                                              short* __restrict__ C,
                                              int M, int N, int K, float oscale) {
  __shared__ short As[128 * 64];
  __shared__ short Bs[128 * 64];
  const int t = threadIdx.x;
  const int lane = t & 63, w = t >> 6;
  const int r = lane & 15, g = lane >> 4;
  const int wr = w >> 1, wc = w & 1;
  const int m0 = blockIdx.y * 128, n0 = blockIdx.x * 128;

  f32x4 acc[4][4] = {};

  for (int k0 = 0; k0 < K; k0 += 64) {
    for (int it = 0; it < 4; ++it) {
      int chunk = it * 4 + w;               // 0..15
      int li = chunk * 64 + lane;           // 0..1023
      int row = li >> 3, cv = li & 7;       // row 0..127, 8-bf16 col group
      const short* gA = A + (size_t)(m0 + row) * K + k0 + cv * 8;
      const short* gB = Bt + (size_t)(n0 + row) * K + k0 + cv * 8;
      __builtin_amdgcn_global_load_lds((const __attribute__((address_space(1))) void*)gA,
                                       (__attribute__((address_space(3))) void*)(As + chunk * 512),
                                       16, 0, 0);
      __builtin_amdgcn_global_load_lds((const __attribute__((address_space(1))) void*)gB,
                                       (__attribute__((address_space(3))) void*)(Bs + chunk * 512),
                                       16, 0, 0);
    }
    __syncthreads();

    for (int kk = 0; kk < 64; kk += 32) {
      bf16x8 a[4], b[4];
#pragma unroll
      for (int m = 0; m < 4; ++m)
        a[m] = *(const bf16x8*)&As[(wr * 64 + m * 16 + r) * 64 + kk + 8 * g];
#pragma unroll
      for (int n = 0; n < 4; ++n)
        b[n] = *(const bf16x8*)&Bs[(wc * 64 + n * 16 + r) * 64 + kk + 8 * g];
#pragma unroll
      for (int m = 0; m < 4; ++m)
#pragma unroll
        for (int n = 0; n < 4; ++n)
          acc[m][n] = __builtin_amdgcn_mfma_f32_16x16x32_bf16(a[m], b[n], acc[m][n], 0, 0, 0);
    }
    __syncthreads();
  }

#pragma unroll
  for (int n = 0; n < 4; ++n) {
    int col = n0 + wc * 64 + n * 16 + r;
    float bv = bias[col];
#pragma unroll
    for (int m = 0; m < 4; ++m) {
      int rowb = m0 + wr * 64 + m * 16 + g * 4;
      if (EPI == 0) {
#pragma unroll
        for (int j = 0; j < 4; ++j)
          C[(size_t)(rowb + j) * N + col] = f2bf((acc[m][n][j] + bv) * oscale);
      } else {
        ushort4 o;
        o.x = (unsigned short)f2bf((acc[m][n][0] + bv) * oscale);
        o.y = (unsigned short)f2bf((acc[m][n][1] + bv) * oscale);
        o.z = (unsigned short)f2bf((acc[m][n][2] + bv) * oscale);
        o.w = (unsigned short)f2bf((acc[m][n][3] + bv) * oscale);
        *(ushort4*)&C[(size_t)col * M + rowb] = o;   // C is [N][M]
      }
    }
  }
}

// ---------------- flash attention, swapped-operand 32x32 structure ----------------
// grid (SEQ/128, NHEADS), 4 waves/block; wave owns 32 q-rows. No LDS, no barriers.
// S^T = mfma(K_frag, Q_frag): lane holds scores for q = lane&31, k-rows spread
// over 16 regs (row=(reg&3)+8*(reg>>2)+4*hi). Softmax fully in-lane + 2 permlane.
// P packed to bf16 via v_cvt_pk_bf16_f32, redistributed with permlane32_swap to
// form PV's B-operand. PV computes O^T = mfma(Vt_frag, P_frag) so the online
// rescale factor is lane-uniform. Defer-max (THR=6) skips most rescales.
__global__ __launch_bounds__(256, 2) void k_attn(const short* __restrict__ Qb,
                                                 const short* __restrict__ Kb,
                                                 const short* __restrict__ Vt,
                                                 float* __restrict__ Out) {
  const int t = threadIdx.x;
  const int lane = t & 63, w = t >> 6;
  const int l31 = lane & 31, hi = lane >> 5;
  const int h = blockIdx.y;
  const int q0 = blockIdx.x * 128 + w * 32;
  const int hoff = h * HDIM;

  // Q fragments: qf[s][j] = Q[q0+l31][hoff + s*16 + hi*8 + j]  (B-operand of QK^T)
  bf16x8 qf[8];
  const short* qp = Qb + (size_t)(q0 + l31) * MDIM + hoff + hi * 8;
#pragma unroll
  for (int s = 0; s < 8; ++s) qf[s] = *(const bf16x8*)(qp + s * 16);

  f32x16 oT[4] = {};
  float mrun = -3.0e38f, lsum = 0.f;

  for (int t0 = 0; t0 < SEQ; t0 += 32) {
    // ---- QK^T: sT[reg] = S[k-row][q=l31], 8 MFMA over D=128 ----
    f32x16 sT = {};
    const short* kp = Kb + (size_t)(t0 + l31) * MDIM + hoff + hi * 8;
#pragma unroll
    for (int s = 0; s < 8; ++s) {
      bf16x8 kf = *(const bf16x8*)(kp + s * 16);
      sT = __builtin_amdgcn_mfma_f32_32x32x16_bf16(kf, qf[s], sT, 0, 0, 0);
    }

    // ---- tile max: in-lane tree over 16, then cross-half permlane swap ----
    float a0 = fmaxf(sT[0], sT[1]),  a1 = fmaxf(sT[2], sT[3]);
    float a2 = fmaxf(sT[4], sT[5]),  a3 = fmaxf(sT[6], sT[7]);
    float a4 = fmaxf(sT[8], sT[9]),  a5 = fmaxf(sT[10], sT[11]);
    float a6 = fmaxf(sT[12], sT[13]), a7 = fmaxf(sT[14], sT[15]);
    float b0 = fmaxf(fmaxf(a0, a1), fmaxf(a2, a3));
    float b1 = fmaxf(fmaxf(a4, a5), fmaxf(a6, a7));
    float tm = fmaxf(b0, b1);
    u32x2 xm = __builtin_amdgcn_permlane32_swap(__float_as_uint(tm), __float_as_uint(tm), false, false);
    float tmall = fmaxf(__uint_as_float(xm.x), __uint_as_float(xm.y));

    // ---- online softmax with defer-max ----
    if (!__all(tmall <= mrun + 6.0f)) {
      float mnew = fmaxf(mrun, tmall);
      float al = __expf(mrun - mnew);
      lsum *= al;
#pragma unroll
      for (int dt = 0; dt < 4; ++dt)
#pragma unroll
        for (int i = 0; i < 16; ++i) oT[dt][i] *= al;
      mrun = mnew;
    }
    float p[16];
#pragma unroll
    for (int i = 0; i < 16; ++i) p[i] = __expf(sT[i] - mrun);
    float r0 = (p[0] + p[1]) + (p[2] + p[3]);
    float r1 = (p[4] + p[5]) + (p[6] + p[7]);
    float r2 = (p[8] + p[9]) + (p[10] + p[11]);
    float r3 = (p[12] + p[13]) + (p[14] + p[15]);
    float rs = (r0 + r1) + (r2 + r3);
    u32x2 xs = __builtin_amdgcn_permlane32_swap(__float_as_uint(rs), __float_as_uint(rs), false, false);
    lsum += __uint_as_float(xs.x) + __uint_as_float(xs.y);

    // ---- pack P to bf16 and redistribute into PV B-operand fragments ----
    unsigned wd[8];
#pragma unroll
    for (int i = 0; i < 8; ++i)
      asm("v_cvt_pk_bf16_f32 %0, %1, %2" : "=v"(wd[i]) : "v"(p[2 * i]), "v"(p[2 * i + 1]));
    u32x2 s1 = __builtin_amdgcn_permlane32_swap(wd[0], wd[2], false, false);
    u32x2 s2 = __builtin_amdgcn_permlane32_swap(wd[1], wd[3], false, false);
    u32x2 t1 = __builtin_amdgcn_permlane32_swap(wd[4], wd[6], false, false);
    u32x2 t2 = __builtin_amdgcn_permlane32_swap(wd[5], wd[7], false, false);
    u32x4 pa0v = {s1.x, s2.x, s1.y, s2.y};   // P[q=l31][k = t0 + 0..15 within half]
    u32x4 pa1v = {t1.x, t2.x, t1.y, t2.y};   // P[q=l31][k = t0 + 16..31]
    bf16x8 pa0 = __builtin_bit_cast(bf16x8, pa0v);
    bf16x8 pa1 = __builtin_bit_cast(bf16x8, pa1v);

    // ---- PV: oT[dt] += mfma(Vt_frag, P_frag); A row = d (lane&31), k = kv idx ----
    const short* vp = Vt + (size_t)(hoff + l31) * SEQ + t0 + hi * 8;
#pragma unroll
    for (int dt = 0; dt < 4; ++dt) {
      bf16x8 v0 = *(const bf16x8*)(vp + (size_t)dt * 32 * SEQ);
      bf16x8 v1 = *(const bf16x8*)(vp + (size_t)dt * 32 * SEQ + 16);
      oT[dt] = __builtin_amdgcn_mfma_f32_32x32x16_bf16(v0, pa0, oT[dt], 0, 0, 0);
      oT[dt] = __builtin_amdgcn_mfma_f32_32x32x16_bf16(v1, pa1, oT[dt], 0, 0, 0);
    }
  }

  // ---- epilogue: O[q][d] = oT[d][q] / lsum; rows d=(reg&3)+8*(reg>>2)+4*hi ----
  float rl = 1.0f / lsum;
  float* orow = Out + (size_t)(q0 + l31) * MDIM + hoff + 4 * hi;
#pragma unroll
  for (int dt = 0; dt < 4; ++dt)
#pragma unroll
    for (int r4 = 0; r4 < 4; ++r4) {
      float4 o4;
      o4.x = oT[dt][r4 * 4 + 0] * rl;
      o4.y = oT[dt][r4 * 4 + 1] * rl;
      o4.z = oT[dt][r4 * 4 + 2] * rl;
      o4.w = oT[dt][r4 * 4 + 3] * rl;
      *(float4*)(orow + dt * 32 + r4 * 8) = o4;
    }
}

extern "C" void kernel_launch(void* const* d_in, const int* in_sizes, int n_in,
                              void* d_out, int out_size, void* d_ws, size_t ws_size,
                              hipStream_t stream) {
  const float* query  = (const float*)d_in[0];
  const float* key_in = (const float*)d_in[1];
  const float* value  = (const float*)d_in[2];
  const float* Wq = (const float*)d_in[3];
  const float* bq = (const float*)d_in[4];
  const float* Wk = (const float*)d_in[5];
  const float* bk = (const float*)d_in[6];
  const float* Wv = (const float*)d_in[7];
  const float* bv = (const float*)d_in[8];
  float* out = (float*)d_out;

  short* Xb  = (short*)d_ws;
  short* Wtb = Xb + (size_t)SEQ * MDIM;
  short* Qb  = Wtb + (size_t)MDIM * MDIM;
  short* Kb  = Qb + (size_t)SEQ * MDIM;
  short* Vt  = Kb + (size_t)SEQ * MDIM;

  const int n4x = SEQ * MDIM / 4;
  dim3 gConv(n4x / 256);
  dim3 gTr(MDIM / 64, MDIM / 64);
  dim3 gGemm(MDIM / 128, SEQ / 128);
  dim3 gAttn(SEQ / 128, NHEADS);
  const float qscale = 0.08838834764831845f; // 1/sqrt(128)

  k_conv<<<gConv, 256, 0, stream>>>(query, Xb, n4x);
  k_transpose<<<gTr, 256, 0, stream>>>(Wq, Wtb);
  k_gemm<0><<<gGemm, 256, 0, stream>>>(Xb, Wtb, bq, Qb, SEQ, MDIM, MDIM, qscale);
  k_conv<<<gConv, 256, 0, stream>>>(key_in, Xb, n4x);
  k_transpose<<<gTr, 256, 0, stream>>>(Wk, Wtb);
  k_gemm<0><<<gGemm, 256, 0, stream>>>(Xb, Wtb, bk, Kb, SEQ, MDIM, MDIM, 1.0f);
  k_conv<<<gConv, 256, 0, stream>>>(value, Xb, n4x);
  k_transpose<<<gTr, 256, 0, stream>>>(Wv, Wtb);
  k_gemm<1><<<gGemm, 256, 0, stream>>>(Xb, Wtb, bv, Vt, SEQ, MDIM, MDIM, 1.0f);
  k_attn<<<gAttn, 256, 0, stream>>>(Qb, Kb, Vt, out);
}